// Round 14
// baseline (208.469 us; speedup 1.0000x reference)
//
#include <hip/hip_runtime.h>
#include <math.h>

#define N_ROWS 131072   // 32*64*64
#define D 64
#define K 512
#define BLK 512                       // 8 waves
#define ROWS_PER_BLK 512              // 64 rows per wave
#define GRID (N_ROWS / ROWS_PER_BLK)  // 256 -> exactly 1 block/CU
#define MARGIN 4e-3f

// d_out layout (floats):
//   [0] loss ; [1..8388608] quantized NCHW ; [8388609] perplexity ;
//   [8388610..] encodings [131072,512]
// d_ws: [0,2048) counts u32[512]; [2048,2056) loss_acc u64 fixed-point;
//       [4096,6144) e2 f32[512]

typedef __attribute__((ext_vector_type(8))) _Float16 f16x8;
typedef __attribute__((ext_vector_type(4))) float    f32x4;

#define MFMA(a, b, c) __builtin_amdgcn_mfma_f32_16x16x32_f16((a), (b), (c), 0, 0, 0)

// LDS arena (143360 B): codebook region [0,131072) doubles as X staging.
#define OFF_EH   0        // [512 codes][128 B] fp16-hi, XOR-swizzled
#define OFF_EL   65536    // fp16-lo
#define OFF_XH   0        // phase A: [512 rows][64] fp16-hi (overwritten by EH)
#define OFF_XL   65536    // phase A: fp16-lo (overwritten by EL)
#define OFF_E2   131072   // f32[512]
#define OFF_IDX  133120   // i32[512]
#define OFF_REF  135168   // i32[512]
#define OFF_HIST 137216   // u32[512]
#define OFF_RED  139264   // f64[512]
#define ARENA_SZ 143360

__global__ __launch_bounds__(256) void vq_e2_kernel(
    const float* __restrict__ emb, float* __restrict__ e2)
{
    int k = blockIdx.x * blockDim.x + threadIdx.x;
    if (k < K) {
        const float* e = emb + k * D;
        float s = 0.f;
        #pragma unroll
        for (int d = 0; d < D; ++d) s = fmaf(e[d], e[d], s);
        e2[k] = s;
    }
}

__device__ __forceinline__ unsigned pk2(_Float16 a, _Float16 b) {
    return (unsigned)__builtin_bit_cast(unsigned short, a) |
           ((unsigned)__builtin_bit_cast(unsigned short, b) << 16);
}

#define CT_ALL(M) M(0) M(1) M(2) M(3)
#define UPD(rt, s, ki) { \
    bool lt1 = (s) < s1_##rt; bool lt2 = (s) < s2_##rt; \
    s2_##rt = lt1 ? s1_##rt : (lt2 ? (s) : s2_##rt); \
    i2_##rt = lt1 ? i1_##rt : (lt2 ? (ki) : i2_##rt); \
    s1_##rt = lt1 ? (s) : s1_##rt; \
    i1_##rt = lt1 ? (ki) : i1_##rt; }

// One distance pass over the full codebook for 32 rows (2 row-tiles of 16).
// Dekker fp16 split, 3 product terms (lo*lo ~1.5e-5 << MARGIN dropped).
// C layout: col=lane&15 -> x-row; row=(lane>>4)*4+j -> code.
__device__ __forceinline__ void dist_pass(
    const char* ebase, const float* e2L, int fq, int fr,
    f16x8 xh0_0, f16x8 xh0_1, f16x8 xl0_0, f16x8 xl0_1,
    f16x8 xh1_0, f16x8 xh1_1, f16x8 xl1_0, f16x8 xl1_1,
    int* s_idxL, int* s_refL, int row0)
{
    float s1_0 = INFINITY, s2_0 = INFINITY, s1_1 = INFINITY, s2_1 = INFINITY;
    int   i1_0 = 0, i2_0 = 0, i1_1 = 0, i2_1 = 0;

    for (int cb = 0; cb < 8; ++cb) {
        const int cbBase = cb * 64 + fq * 4;

#define LDE2(ct) f32x4 e2q##ct = *(const f32x4*)(e2L + cb * 64 + ct * 16 + fq * 4);
        CT_ALL(LDE2)
#undef LDE2

#define LDE(ct) \
        const int c##ct = cb * 64 + ct * 16 + fr; \
        const char* rb##ct = ebase + c##ct * 128; \
        const unsigned xr##ct = (unsigned)((c##ct & 7) << 4); \
        f16x8 eh##ct##_0 = *(const f16x8*)(rb##ct + OFF_EH + (((unsigned)(fq*16 +  0)) ^ xr##ct)); \
        f16x8 eh##ct##_1 = *(const f16x8*)(rb##ct + OFF_EH + (((unsigned)(fq*16 + 64)) ^ xr##ct)); \
        f16x8 el##ct##_0 = *(const f16x8*)(rb##ct + OFF_EL + (((unsigned)(fq*16 +  0)) ^ xr##ct)); \
        f16x8 el##ct##_1 = *(const f16x8*)(rb##ct + OFF_EL + (((unsigned)(fq*16 + 64)) ^ xr##ct));
        CT_ALL(LDE)
#undef LDE

#define ACC1(rt, ct) \
        f32x4 a##rt##_##ct = {0.f, 0.f, 0.f, 0.f}; \
        a##rt##_##ct = MFMA(eh##ct##_0, xh##rt##_0, a##rt##_##ct); \
        a##rt##_##ct = MFMA(eh##ct##_1, xh##rt##_1, a##rt##_##ct); \
        a##rt##_##ct = MFMA(el##ct##_0, xh##rt##_0, a##rt##_##ct); \
        a##rt##_##ct = MFMA(el##ct##_1, xh##rt##_1, a##rt##_##ct); \
        a##rt##_##ct = MFMA(eh##ct##_0, xl##rt##_0, a##rt##_##ct); \
        a##rt##_##ct = MFMA(eh##ct##_1, xl##rt##_1, a##rt##_##ct);
#define ACC_CT(ct) ACC1(0, ct) ACC1(1, ct)
        CT_ALL(ACC_CT)
#undef ACC_CT
#undef ACC1

#define SCJ(rt, ct, j) { \
        float s = fmaf(-2.f, a##rt##_##ct[j], e2q##ct[j]); \
        int ki = cbBase + ct * 16 + j; \
        UPD(rt, s, ki) }
#define SC4(rt, ct) SCJ(rt, ct, 0) SCJ(rt, ct, 1) SCJ(rt, ct, 2) SCJ(rt, ct, 3)
#define SC_CT(ct) SC4(0, ct) SC4(1, ct)
        CT_ALL(SC_CT)
#undef SC_CT
#undef SC4
#undef SCJ
    }

    // cross-lane top-2 merge (fq groups 0..3 see disjoint codes)
#define MERGE(rt, off) { \
    float b1 = __shfl_xor(s1_##rt, off); int bi1 = __shfl_xor(i1_##rt, off); \
    float b2 = __shfl_xor(s2_##rt, off); int bi2 = __shfl_xor(i2_##rt, off); \
    bool bf = (b1 < s1_##rt) || (b1 == s1_##rt && bi1 < i1_##rt); \
    float c1 = bf ? b1 : s1_##rt; int ci1 = bf ? bi1 : i1_##rt; \
    float lw = bf ? s1_##rt : b1; int lwi = bf ? i1_##rt : bi1; \
    float d2 = bf ? b2 : s2_##rt; int di2 = bf ? bi2 : i2_##rt; \
    bool ds = (d2 < lw) || (d2 == lw && di2 < lwi); \
    s1_##rt = c1; i1_##rt = ci1; \
    s2_##rt = ds ? d2 : lw; i2_##rt = ds ? di2 : lwi; }
    MERGE(0, 16) MERGE(0, 32) MERGE(1, 16) MERGE(1, 32)
#undef MERGE

    if (fq == 0) {
        s_idxL[row0 + fr] = i1_0;
        s_refL[row0 + fr] = (s2_0 - s1_0 < MARGIN) ? i2_0 : -1;
        s_idxL[row0 + fr + 16] = i1_1;
        s_refL[row0 + fr + 16] = (s2_1 - s1_1 < MARGIN) ? i2_1 : -1;
    }
}

// Round-14: NT stores REVERTED (R13 counters: WRITE 416 MB vs 302 MB
// algorithmic -- NT bypassed L2 write-combining and inflated HBM write
// traffic ~40%, dur 150->179). Plain stores restore L2 merging. Also:
// P0 x-staging writes were a 32-way bank conflict (4B/lane at 128B row
// stride, 2.24M SQ_LDS_BANK_CONFLICT) -> XOR-swizzle in-row offset with
// (row&7)<<4, mirrored in the P1 fragment reads. Wave-independent
// (no-barrier) structure from R13 kept.
__global__ __launch_bounds__(BLK, 2) void vq_main_kernel(
    const float* __restrict__ in,     // [32,64,64,64] NCHW
    const float* __restrict__ emb,    // [512,64]
    const float* __restrict__ e2g,    // [512]
    unsigned int* __restrict__ counts,
    unsigned long long* __restrict__ loss_acc,
    float* __restrict__ quant_out,    // NCHW
    float* __restrict__ enc_out)      // [N_ROWS, 512]
{
    __shared__ __align__(16) char s_arena[ARENA_SZ];
    float*        e2L    = (float*)(s_arena + OFF_E2);
    int*          s_idxL = (int*)(s_arena + OFF_IDX);
    int*          s_refL = (int*)(s_arena + OFF_REF);
    unsigned int* s_hstL = (unsigned int*)(s_arena + OFF_HIST);
    double*       s_redL = (double*)(s_arena + OFF_RED);

    const int tid  = threadIdx.x;
    const int lane = tid & 63;
    const int w    = tid >> 6;      // wave 0..7
    const int fr   = lane & 15;
    const int fq   = lane >> 4;

    // ---- P0: stage x split into LDS [512 rows][128 B] fp16, XOR-swizzled
    //      (in-row byte offset ^ (row&7)<<4 -> spreads the 128B-stride
    //       writes across 8 bank-slots instead of all hitting bank 0) ----
    {
        const int nn = blockIdx.x * ROWS_PER_BLK + tid;
        const int bb = nn >> 12, hww = nn & 4095;
        const float* xp = in + (size_t)bb * 262144 + hww;
        char* xhW = s_arena + OFF_XH;
        char* xlW = s_arena + OFF_XL;
        const unsigned rbase = (unsigned)tid * 128u;
        const unsigned rxor  = (unsigned)((tid & 7) << 4);
        #pragma unroll
        for (int i = 0; i < 64; i += 2) {
            float f0 = xp[i * 4096];
            float f1 = xp[(i + 1) * 4096];
            _Float16 h0 = (_Float16)f0; _Float16 l0 = (_Float16)(f0 - (float)h0);
            _Float16 h1 = (_Float16)f1; _Float16 l1 = (_Float16)(f1 - (float)h1);
            unsigned off = rbase + (((unsigned)(i * 2)) ^ rxor);
            *(unsigned*)(xhW + off) = pk2(h0, h1);
            *(unsigned*)(xlW + off) = pk2(l0, l1);
        }
    }
    __syncthreads();

    // ---- P1: load ALL 4 row-tiles' X fragments (16 f16x8 = 64 VGPR),
    //      applying the matching XOR on the 16B-aligned offsets ----
    const char* xb = s_arena;
    const int xr0 = w * 64 + fr;
#define LDX1(t, half) \
    *(const f16x8*)(xb + OFF_XH + (unsigned)(xr0 + t * 16) * 128u + \
        (((unsigned)(fq * 16 + half * 64)) ^ ((unsigned)(((xr0 + t * 16) & 7) << 4))))
#define LDX1L(t, half) \
    *(const f16x8*)(xb + OFF_XL + (unsigned)(xr0 + t * 16) * 128u + \
        (((unsigned)(fq * 16 + half * 64)) ^ ((unsigned)(((xr0 + t * 16) & 7) << 4))))
#define LDXF(t) \
    f16x8 xh##t##_0 = LDX1(t, 0); \
    f16x8 xh##t##_1 = LDX1(t, 1); \
    f16x8 xl##t##_0 = LDX1L(t, 0); \
    f16x8 xl##t##_1 = LDX1L(t, 1);
    LDXF(0) LDXF(1) LDXF(2) LDXF(3)
#undef LDXF
#undef LDX1
#undef LDX1L
    __syncthreads();

    // ---- P2: overwrite LDS with split codebook (XOR-swizzled rows) ----
    {
        char* eb = s_arena;
        #pragma unroll
        for (int it = 0; it < 16; ++it) {
            int j = tid + it * 512;            // float4 index, 0..8191
            int c = j >> 4, q = j & 15;        // code, quad-within-row
            float4 e = ((const float4*)emb)[j];
            _Float16 h0 = (_Float16)e.x; _Float16 l0 = (_Float16)(e.x - (float)h0);
            _Float16 h1 = (_Float16)e.y; _Float16 l1 = (_Float16)(e.y - (float)h1);
            _Float16 h2 = (_Float16)e.z; _Float16 l2 = (_Float16)(e.z - (float)h2);
            _Float16 h3 = (_Float16)e.w; _Float16 l3 = (_Float16)(e.w - (float)h3);
            unsigned xr = (unsigned)((c & 7) << 4);
            unsigned base = (unsigned)(c * 128) + (((unsigned)(q * 8)) ^ xr);
            *(uint2*)(eb + OFF_EH + base) = make_uint2(pk2(h0, h1), pk2(h2, h3));
            *(uint2*)(eb + OFF_EL + base) = make_uint2(pk2(l0, l1), pk2(l2, l3));
        }
        e2L[tid] = e2g[tid];
        s_hstL[tid] = 0u;
    }
    __syncthreads();

    // ---- From here: NO block syncs until the loss/hist epilogue. ----

    // P3: two distance passes for this wave's 64 rows
    dist_pass(s_arena, e2L, fq, fr,
              xh0_0, xh0_1, xl0_0, xl0_1, xh1_0, xh1_1, xl1_0, xl1_1,
              s_idxL, s_refL, w * 64);
    dist_pass(s_arena, e2L, fq, fr,
              xh2_0, xh2_1, xl2_0, xl2_1, xh3_0, xh3_1, xl3_0, xl3_1,
              s_idxL, s_refL, w * 64 + 32);

    // P4: per-row outputs (thread tid -> row tid; same wave as producer)
    float lsum = 0.f;
    {
        const int n = blockIdx.x * ROWS_PER_BLK + tid;
        const int b = n >> 12, hw = n & 4095;
        const float* xin = in + (size_t)b * 262144 + hw;
        int i1 = s_idxL[tid];
        const int ir = s_refL[tid];
        if (ir >= 0) {   // fp64 refinement on near-ties (argmin fp64-exact)
            double dA = 0.0, dB = 0.0;
            const float* eA = emb + i1 * D;
            const float* eB = emb + ir * D;
            for (int d = 0; d < D; ++d) {
                double xv = (double)xin[d * 4096];
                double tA = xv - (double)eA[d]; dA = fma(tA, tA, dA);
                double tB = xv - (double)eB[d]; dB = fma(tB, tB, dB);
            }
            if (dB < dA || (dB == dA && ir < i1)) { i1 = ir; s_idxL[tid] = ir; }
        }
        atomicAdd(&s_hstL[i1], 1u);

        // quantized write (exact fp32 codebook row from global) + loss
        const float4* eq = (const float4*)(emb + (size_t)i1 * D);
        float* qout = quant_out + (size_t)b * 262144 + hw;
        #pragma unroll
        for (int i = 0; i < 16; ++i) {
            float4 q = eq[i];
            float x0 = xin[(4 * i + 0) * 4096], x1 = xin[(4 * i + 1) * 4096];
            float x2 = xin[(4 * i + 2) * 4096], x3 = xin[(4 * i + 3) * 4096];
            float d0 = q.x - x0; lsum = fmaf(d0, d0, lsum);
            float d1 = q.y - x1; lsum = fmaf(d1, d1, lsum);
            float d2 = q.z - x2; lsum = fmaf(d2, d2, lsum);
            float d3 = q.w - x3; lsum = fmaf(d3, d3, lsum);
            qout[(4 * i + 0) * 4096] = q.x;
            qout[(4 * i + 1) * 4096] = q.y;
            qout[(4 * i + 2) * 4096] = q.z;
            qout[(4 * i + 3) * 4096] = q.w;
        }
    }
    s_redL[tid] = (double)lsum;

    // P5: wave-local one-hot expansion for this wave's 64 rows.
    // Lane covers cols [lane*8, lane*8+8) of each row -> 2 KB contiguous/row.
    {
        float* wrow = enc_out +
            ((size_t)blockIdx.x * ROWS_PER_BLK + (size_t)w * 64) * K;
        const int c0 = lane * 8;
        #pragma unroll 8
        for (int i = 0; i < 64; ++i) {
            const int idx = s_idxL[w * 64 + i];   // wave-uniform
            float4 v0, v1;
            v0.x = (c0 + 0 == idx) ? 1.f : 0.f;
            v0.y = (c0 + 1 == idx) ? 1.f : 0.f;
            v0.z = (c0 + 2 == idx) ? 1.f : 0.f;
            v0.w = (c0 + 3 == idx) ? 1.f : 0.f;
            v1.x = (c0 + 4 == idx) ? 1.f : 0.f;
            v1.y = (c0 + 5 == idx) ? 1.f : 0.f;
            v1.z = (c0 + 6 == idx) ? 1.f : 0.f;
            v1.w = (c0 + 7 == idx) ? 1.f : 0.f;
            float* rp = wrow + (size_t)i * K + c0;
            *reinterpret_cast<float4*>(rp) = v0;
            *reinterpret_cast<float4*>(rp + 4) = v1;
        }
    }

    // ---- Epilogue: block loss reduction + histogram flush ----
    __syncthreads();
    for (int s = BLK / 2; s > 0; s >>= 1) {
        if (tid < s) s_redL[tid] += s_redL[tid + s];
        __syncthreads();
    }
    if (tid == 0) {
        unsigned long long q =
            (unsigned long long)(long long)llrint(s_redL[0] * 1073741824.0);
        atomicAdd(loss_acc, q);
    }
    {
        unsigned int c = s_hstL[tid];
        if (c) atomicAdd(&counts[tid], c);
    }
}

__global__ __launch_bounds__(512) void vq_final_kernel(
    const unsigned int* __restrict__ counts,
    const unsigned long long* __restrict__ loss_acc,
    float* __restrict__ out_loss,
    float* __restrict__ out_perp)
{
    __shared__ double sp[512];
    int t = threadIdx.x;
    double p = (double)counts[t] / (double)N_ROWS;
    sp[t] = p * log(p + 1e-10);
    __syncthreads();
    for (int s = 256; s > 0; s >>= 1) {
        if (t < s) sp[t] += sp[t + s];
        __syncthreads();
    }
    if (t == 0) {
        double ls = (double)(long long)(*loss_acc) * (1.0 / 1073741824.0);
        *out_loss = (float)(0.25 * ls / 8388608.0);
        *out_perp = (float)exp(-sp[0]);
    }
}

extern "C" void kernel_launch(void* const* d_in, const int* in_sizes, int n_in,
                              void* d_out, int out_size, void* d_ws, size_t ws_size,
                              hipStream_t stream) {
    const float* in  = (const float*)d_in[0];
    const float* emb = (const float*)d_in[1];
    float* out = (float*)d_out;

    unsigned int* counts = (unsigned int*)d_ws;
    unsigned long long* loss_acc = (unsigned long long*)((char*)d_ws + 2048);
    float* e2 = (float*)((char*)d_ws + 4096);

    hipMemsetAsync(d_ws, 0, 2056, stream);
    vq_e2_kernel<<<2, 256, 0, stream>>>(emb, e2);
    vq_main_kernel<<<GRID, BLK, 0, stream>>>(in, emb, e2, counts, loss_acc,
                                             out + 1, out + 8388610);
    vq_final_kernel<<<1, 512, 0, stream>>>(counts, loss_acc, out, out + 8388609);
}

// Round 15
// 129.676 us; speedup vs baseline: 1.6076x; 1.6076x over previous
//
#include <hip/hip_runtime.h>
#include <math.h>

#define N_ROWS 131072   // 32*64*64
#define D 64
#define K 512
#define BLK 512                       // 8 waves (K1)
#define ROWS_PER_BLK 512
#define GRID (N_ROWS / ROWS_PER_BLK)  // 256 -> 1 block/CU for K1
#define MARGIN 4e-3f

// d_out layout (floats):
//   [0] loss ; [1..8388608] quantized NCHW ; [8388609] perplexity ;
//   [8388610..] encodings [131072,512]
// d_ws: [0,2048) counts u32[512]; [2048,2056) loss_acc u64 fixed-point;
//       [4096,6144) e2 f32[512]

typedef __attribute__((ext_vector_type(8))) _Float16 f16x8;
typedef __attribute__((ext_vector_type(4))) float    f32x4;

#define MFMA(a, b, c) __builtin_amdgcn_mfma_f32_16x16x32_f16((a), (b), (c), 0, 0, 0)

// K1 LDS arena (137216 B): codebook region [0,131072) doubles as X staging.
#define OFF_EH   0        // [512 codes][128 B] fp16-hi, XOR-swizzled
#define OFF_EL   65536    // fp16-lo
#define OFF_XH   0        // phase A: [512 rows][128 B] fp16-hi (overwritten)
#define OFF_XL   65536    // phase A: fp16-lo
#define OFF_E2   131072   // f32[512]
#define OFF_IDX  133120   // i32[512]
#define OFF_REF  135168   // i32[512]
#define ARENA_SZ 137216

__global__ __launch_bounds__(256) void vq_e2_kernel(
    const float* __restrict__ emb, float* __restrict__ e2)
{
    int k = blockIdx.x * blockDim.x + threadIdx.x;
    if (k < K) {
        const float* e = emb + k * D;
        float s = 0.f;
        #pragma unroll
        for (int d = 0; d < D; ++d) s = fmaf(e[d], e[d], s);
        e2[k] = s;
    }
}

__device__ __forceinline__ unsigned pk2(_Float16 a, _Float16 b) {
    return (unsigned)__builtin_bit_cast(unsigned short, a) |
           ((unsigned)__builtin_bit_cast(unsigned short, b) << 16);
}

#define CT_ALL(M) M(0) M(1) M(2) M(3)
#define UPD(rt, s, ki) { \
    bool lt1 = (s) < s1_##rt; bool lt2 = (s) < s2_##rt; \
    s2_##rt = lt1 ? s1_##rt : (lt2 ? (s) : s2_##rt); \
    i2_##rt = lt1 ? i1_##rt : (lt2 ? (ki) : i2_##rt); \
    s1_##rt = lt1 ? (s) : s1_##rt; \
    i1_##rt = lt1 ? (ki) : i1_##rt; }

// One distance pass over the full codebook for 32 rows (2 row-tiles of 16).
// Dekker fp16 split, 3 product terms (lo*lo ~1.5e-5 << MARGIN dropped).
// C layout: col=lane&15 -> x-row; row=(lane>>4)*4+j -> code.
__device__ __forceinline__ void dist_pass(
    const char* ebase, const float* e2L, int fq, int fr,
    f16x8 xh0_0, f16x8 xh0_1, f16x8 xl0_0, f16x8 xl0_1,
    f16x8 xh1_0, f16x8 xh1_1, f16x8 xl1_0, f16x8 xl1_1,
    int* s_idxL, int* s_refL, int row0)
{
    float s1_0 = INFINITY, s2_0 = INFINITY, s1_1 = INFINITY, s2_1 = INFINITY;
    int   i1_0 = 0, i2_0 = 0, i1_1 = 0, i2_1 = 0;

    for (int cb = 0; cb < 8; ++cb) {
        const int cbBase = cb * 64 + fq * 4;

#define LDE2(ct) f32x4 e2q##ct = *(const f32x4*)(e2L + cb * 64 + ct * 16 + fq * 4);
        CT_ALL(LDE2)
#undef LDE2

#define LDE(ct) \
        const int c##ct = cb * 64 + ct * 16 + fr; \
        const char* rb##ct = ebase + c##ct * 128; \
        const unsigned xr##ct = (unsigned)((c##ct & 7) << 4); \
        f16x8 eh##ct##_0 = *(const f16x8*)(rb##ct + OFF_EH + (((unsigned)(fq*16 +  0)) ^ xr##ct)); \
        f16x8 eh##ct##_1 = *(const f16x8*)(rb##ct + OFF_EH + (((unsigned)(fq*16 + 64)) ^ xr##ct)); \
        f16x8 el##ct##_0 = *(const f16x8*)(rb##ct + OFF_EL + (((unsigned)(fq*16 +  0)) ^ xr##ct)); \
        f16x8 el##ct##_1 = *(const f16x8*)(rb##ct + OFF_EL + (((unsigned)(fq*16 + 64)) ^ xr##ct));
        CT_ALL(LDE)
#undef LDE

#define ACC1(rt, ct) \
        f32x4 a##rt##_##ct = {0.f, 0.f, 0.f, 0.f}; \
        a##rt##_##ct = MFMA(eh##ct##_0, xh##rt##_0, a##rt##_##ct); \
        a##rt##_##ct = MFMA(eh##ct##_1, xh##rt##_1, a##rt##_##ct); \
        a##rt##_##ct = MFMA(el##ct##_0, xh##rt##_0, a##rt##_##ct); \
        a##rt##_##ct = MFMA(el##ct##_1, xh##rt##_1, a##rt##_##ct); \
        a##rt##_##ct = MFMA(eh##ct##_0, xl##rt##_0, a##rt##_##ct); \
        a##rt##_##ct = MFMA(eh##ct##_1, xl##rt##_1, a##rt##_##ct);
#define ACC_CT(ct) ACC1(0, ct) ACC1(1, ct)
        CT_ALL(ACC_CT)
#undef ACC_CT
#undef ACC1

#define SCJ(rt, ct, j) { \
        float s = fmaf(-2.f, a##rt##_##ct[j], e2q##ct[j]); \
        int ki = cbBase + ct * 16 + j; \
        UPD(rt, s, ki) }
#define SC4(rt, ct) SCJ(rt, ct, 0) SCJ(rt, ct, 1) SCJ(rt, ct, 2) SCJ(rt, ct, 3)
#define SC_CT(ct) SC4(0, ct) SC4(1, ct)
        CT_ALL(SC_CT)
#undef SC_CT
#undef SC4
#undef SCJ
    }

    // cross-lane top-2 merge (fq groups 0..3 see disjoint codes)
#define MERGE(rt, off) { \
    float b1 = __shfl_xor(s1_##rt, off); int bi1 = __shfl_xor(i1_##rt, off); \
    float b2 = __shfl_xor(s2_##rt, off); int bi2 = __shfl_xor(i2_##rt, off); \
    bool bf = (b1 < s1_##rt) || (b1 == s1_##rt && bi1 < i1_##rt); \
    float c1 = bf ? b1 : s1_##rt; int ci1 = bf ? bi1 : i1_##rt; \
    float lw = bf ? s1_##rt : b1; int lwi = bf ? i1_##rt : bi1; \
    float d2 = bf ? b2 : s2_##rt; int di2 = bf ? bi2 : i2_##rt; \
    bool ds = (d2 < lw) || (d2 == lw && di2 < lwi); \
    s1_##rt = c1; i1_##rt = ci1; \
    s2_##rt = ds ? d2 : lw; i2_##rt = ds ? di2 : lwi; }
    MERGE(0, 16) MERGE(0, 32) MERGE(1, 16) MERGE(1, 32)
#undef MERGE

    if (fq == 0) {
        s_idxL[row0 + fr] = i1_0;
        s_refL[row0 + fr] = (s2_0 - s1_0 < MARGIN) ? i2_0 : -1;
        s_idxL[row0 + fr + 16] = i1_1;
        s_refL[row0 + fr + 16] = (s2_1 - s1_1 < MARGIN) ? i2_1 : -1;
    }
}

// K1: the MFMA distance machine ONLY (ablation round 15: per-kernel rocprof
// timing localizes the ~120 us my component model cannot explain). Writes
// packed (i1 | (i2cand+1)<<16) into the first 4 bytes of each row's enc slot.
__global__ __launch_bounds__(BLK, 2) void vq_dist_kernel(
    const float* __restrict__ in,     // [32,64,64,64] NCHW
    const float* __restrict__ emb,    // [512,64]
    const float* __restrict__ e2g,    // [512]
    float* __restrict__ enc_out)      // [N_ROWS, 512]
{
    __shared__ __align__(16) char s_arena[ARENA_SZ];
    float* e2L    = (float*)(s_arena + OFF_E2);
    int*   s_idxL = (int*)(s_arena + OFF_IDX);
    int*   s_refL = (int*)(s_arena + OFF_REF);

    const int tid  = threadIdx.x;
    const int lane = tid & 63;
    const int w    = tid >> 6;
    const int fr   = lane & 15;
    const int fq   = lane >> 4;

    // P0: stage x split into LDS [512 rows][128 B] fp16, XOR-swizzled
    {
        const int nn = blockIdx.x * ROWS_PER_BLK + tid;
        const int bb = nn >> 12, hww = nn & 4095;
        const float* xp = in + (size_t)bb * 262144 + hww;
        char* xhW = s_arena + OFF_XH;
        char* xlW = s_arena + OFF_XL;
        const unsigned rbase = (unsigned)tid * 128u;
        const unsigned rxor  = (unsigned)((tid & 7) << 4);
        #pragma unroll
        for (int i = 0; i < 64; i += 2) {
            float f0 = xp[i * 4096];
            float f1 = xp[(i + 1) * 4096];
            _Float16 h0 = (_Float16)f0; _Float16 l0 = (_Float16)(f0 - (float)h0);
            _Float16 h1 = (_Float16)f1; _Float16 l1 = (_Float16)(f1 - (float)h1);
            unsigned off = rbase + (((unsigned)(i * 2)) ^ rxor);
            *(unsigned*)(xhW + off) = pk2(h0, h1);
            *(unsigned*)(xlW + off) = pk2(l0, l1);
        }
    }
    __syncthreads();

    // P1: load ALL 4 row-tiles' X fragments (matching XOR on 16B offsets)
    const char* xb = s_arena;
    const int xr0 = w * 64 + fr;
#define LDX1(t, half) \
    *(const f16x8*)(xb + OFF_XH + (unsigned)(xr0 + t * 16) * 128u + \
        (((unsigned)(fq * 16 + half * 64)) ^ ((unsigned)(((xr0 + t * 16) & 7) << 4))))
#define LDX1L(t, half) \
    *(const f16x8*)(xb + OFF_XL + (unsigned)(xr0 + t * 16) * 128u + \
        (((unsigned)(fq * 16 + half * 64)) ^ ((unsigned)(((xr0 + t * 16) & 7) << 4))))
#define LDXF(t) \
    f16x8 xh##t##_0 = LDX1(t, 0); \
    f16x8 xh##t##_1 = LDX1(t, 1); \
    f16x8 xl##t##_0 = LDX1L(t, 0); \
    f16x8 xl##t##_1 = LDX1L(t, 1);
    LDXF(0) LDXF(1) LDXF(2) LDXF(3)
#undef LDXF
#undef LDX1
#undef LDX1L
    __syncthreads();

    // P2: overwrite LDS with split codebook (XOR-swizzled rows) + e2
    {
        char* eb = s_arena;
        #pragma unroll
        for (int it = 0; it < 16; ++it) {
            int j = tid + it * 512;
            int c = j >> 4, q = j & 15;
            float4 e = ((const float4*)emb)[j];
            _Float16 h0 = (_Float16)e.x; _Float16 l0 = (_Float16)(e.x - (float)h0);
            _Float16 h1 = (_Float16)e.y; _Float16 l1 = (_Float16)(e.y - (float)h1);
            _Float16 h2 = (_Float16)e.z; _Float16 l2 = (_Float16)(e.z - (float)h2);
            _Float16 h3 = (_Float16)e.w; _Float16 l3 = (_Float16)(e.w - (float)h3);
            unsigned xr = (unsigned)((c & 7) << 4);
            unsigned base = (unsigned)(c * 128) + (((unsigned)(q * 8)) ^ xr);
            *(uint2*)(eb + OFF_EH + base) = make_uint2(pk2(h0, h1), pk2(h2, h3));
            *(uint2*)(eb + OFF_EL + base) = make_uint2(pk2(l0, l1), pk2(l2, l3));
        }
        e2L[tid] = e2g[tid];
    }
    __syncthreads();

    // P3: two distance passes for this wave's 64 rows
    dist_pass(s_arena, e2L, fq, fr,
              xh0_0, xh0_1, xl0_0, xl0_1, xh1_0, xh1_1, xl1_0, xl1_1,
              s_idxL, s_refL, w * 64);
    dist_pass(s_arena, e2L, fq, fr,
              xh2_0, xh2_1, xl2_0, xl2_1, xh3_0, xh3_1, xl3_0, xl3_1,
              s_idxL, s_refL, w * 64 + 32);

    // pack (i1, ref) into the row's enc slot (same wave produced both)
    {
        const int n = blockIdx.x * ROWS_PER_BLK + tid;
        int i1 = s_idxL[tid];
        int ir = s_refL[tid];
        *(int*)(enc_out + (size_t)n * K) = i1 | ((ir + 1) << 16);
    }
}

// K2: high-occupancy outputs: refine ties (fp64), final idx -> enc slot,
// histogram, quantized NCHW write (dense NT scalar stores) + loss.
__global__ __launch_bounds__(256) void vq_out_kernel(
    const float* __restrict__ in,
    const float* __restrict__ emb,
    unsigned int* __restrict__ counts,
    unsigned long long* __restrict__ loss_acc,
    float* __restrict__ quant_out,
    float* __restrict__ enc)
{
    __shared__ unsigned int s_hist[K];
    __shared__ double s_red[256];
    const int tid = threadIdx.x;
    const int n = blockIdx.x * 256 + tid;
    s_hist[tid] = 0u; s_hist[tid + 256] = 0u;
    __syncthreads();

    const int b = n >> 12, hw = n & 4095;
    const float* xin = in + (size_t)b * 262144 + hw;
    const int packed = *(const int*)(enc + (size_t)n * K);
    int i1 = packed & 0xFFFF;
    const int ir = (packed >> 16) - 1;
    if (ir >= 0) {   // fp64 refinement on near-ties (argmin fp64-exact)
        double dA = 0.0, dB = 0.0;
        const float* eA = emb + i1 * D;
        const float* eB = emb + ir * D;
        for (int d = 0; d < D; ++d) {
            double xv = (double)xin[d * 4096];
            double tA = xv - (double)eA[d]; dA = fma(tA, tA, dA);
            double tB = xv - (double)eB[d]; dB = fma(tB, tB, dB);
        }
        if (dB < dA || (dB == dA && ir < i1)) i1 = ir;
    }
    *(int*)(enc + (size_t)n * K) = i1;     // final idx for K3
    atomicAdd(&s_hist[i1], 1u);

    // quant write (dense 256 B/instr per wave -> NT safe) + loss
    const float4* eq = (const float4*)(emb + (size_t)i1 * D);
    float* qout = quant_out + (size_t)b * 262144 + hw;
    float lsum = 0.f;
    #pragma unroll
    for (int i = 0; i < 16; ++i) {
        float4 q = eq[i];
        float x0 = xin[(4 * i + 0) * 4096], x1 = xin[(4 * i + 1) * 4096];
        float x2 = xin[(4 * i + 2) * 4096], x3 = xin[(4 * i + 3) * 4096];
        float d0 = q.x - x0; lsum = fmaf(d0, d0, lsum);
        float d1 = q.y - x1; lsum = fmaf(d1, d1, lsum);
        float d2 = q.z - x2; lsum = fmaf(d2, d2, lsum);
        float d3 = q.w - x3; lsum = fmaf(d3, d3, lsum);
        __builtin_nontemporal_store(q.x, &qout[(4 * i + 0) * 4096]);
        __builtin_nontemporal_store(q.y, &qout[(4 * i + 1) * 4096]);
        __builtin_nontemporal_store(q.z, &qout[(4 * i + 2) * 4096]);
        __builtin_nontemporal_store(q.w, &qout[(4 * i + 3) * 4096]);
    }

    s_red[tid] = (double)lsum;
    __syncthreads();
    for (int s = 128; s > 0; s >>= 1) {
        if (tid < s) s_red[tid] += s_red[tid + s];
        __syncthreads();
    }
    if (tid == 0) {
        unsigned long long q =
            (unsigned long long)(long long)llrint(s_red[0] * 1073741824.0);
        atomicAdd(loss_acc, q);
    }
    {
        unsigned int c0 = s_hist[tid];
        if (c0) atomicAdd(&counts[tid], c0);
        unsigned int c1 = s_hist[tid + 256];
        if (c1) atomicAdd(&counts[tid + 256], c1);
    }
}

// K3: one-hot expansion, DENSE-per-instruction NT stores (lane*16B
// contiguous 1 KB per instr; R13 lesson: half-dense NT inflates HBM writes).
__global__ __launch_bounds__(256) void vq_enc_kernel(float* __restrict__ enc)
{
    const int tid  = threadIdx.x;
    const int wv   = tid >> 6;
    const int lane = tid & 63;
    const size_t row0 = (size_t)blockIdx.x * 64 + (size_t)wv * 16;

    int idxs[16];
    #pragma unroll
    for (int i = 0; i < 16; ++i)
        idxs[i] = *(const int*)(enc + (row0 + i) * K);

    const int c0 = lane * 4;
    #pragma unroll
    for (int i = 0; i < 16; ++i) {
        const int idx = idxs[i];
        float* rp = enc + (row0 + i) * K;
        f32x4 v0, v1;
        v0.x = (c0 + 0 == idx) ? 1.f : 0.f;
        v0.y = (c0 + 1 == idx) ? 1.f : 0.f;
        v0.z = (c0 + 2 == idx) ? 1.f : 0.f;
        v0.w = (c0 + 3 == idx) ? 1.f : 0.f;
        v1.x = (256 + c0 + 0 == idx) ? 1.f : 0.f;
        v1.y = (256 + c0 + 1 == idx) ? 1.f : 0.f;
        v1.z = (256 + c0 + 2 == idx) ? 1.f : 0.f;
        v1.w = (256 + c0 + 3 == idx) ? 1.f : 0.f;
        __builtin_nontemporal_store(v0, (f32x4*)(rp + c0));
        __builtin_nontemporal_store(v1, (f32x4*)(rp + 256 + c0));
    }
}

__global__ __launch_bounds__(512) void vq_final_kernel(
    const unsigned int* __restrict__ counts,
    const unsigned long long* __restrict__ loss_acc,
    float* __restrict__ out_loss,
    float* __restrict__ out_perp)
{
    __shared__ double sp[512];
    int t = threadIdx.x;
    double p = (double)counts[t] / (double)N_ROWS;
    sp[t] = p * log(p + 1e-10);
    __syncthreads();
    for (int s = 256; s > 0; s >>= 1) {
        if (t < s) sp[t] += sp[t + s];
        __syncthreads();
    }
    if (t == 0) {
        double ls = (double)(long long)(*loss_acc) * (1.0 / 1073741824.0);
        *out_loss = (float)(0.25 * ls / 8388608.0);
        *out_perp = (float)exp(-sp[0]);
    }
}

extern "C" void kernel_launch(void* const* d_in, const int* in_sizes, int n_in,
                              void* d_out, int out_size, void* d_ws, size_t ws_size,
                              hipStream_t stream) {
    const float* in  = (const float*)d_in[0];
    const float* emb = (const float*)d_in[1];
    float* out = (float*)d_out;

    unsigned int* counts = (unsigned int*)d_ws;
    unsigned long long* loss_acc = (unsigned long long*)((char*)d_ws + 2048);
    float* e2 = (float*)((char*)d_ws + 4096);

    hipMemsetAsync(d_ws, 0, 2056, stream);
    vq_e2_kernel<<<2, 256, 0, stream>>>(emb, e2);
    vq_dist_kernel<<<GRID, BLK, 0, stream>>>(in, emb, e2, out + 8388610);
    vq_out_kernel<<<N_ROWS / 256, 256, 0, stream>>>(in, emb, counts, loss_acc,
                                                    out + 1, out + 8388610);
    vq_enc_kernel<<<N_ROWS / 64, 256, 0, stream>>>(out + 8388610);
    vq_final_kernel<<<1, 512, 0, stream>>>(counts, loss_acc, out, out + 8388609);
}